// Round 14
// baseline (307.686 us; speedup 1.0000x reference)
//
#include <hip/hip_runtime.h>

#define B_ 4
#define T_ 2048
#define D_ 1024
#define H_ 16
#define DK_ 64
#define M_ (B_*T_)   // 8192 rows

typedef __bf16 bf16;
typedef __bf16 bf16x8 __attribute__((ext_vector_type(8)));
typedef __bf16 bf16x4 __attribute__((ext_vector_type(4)));
typedef short s16x4 __attribute__((ext_vector_type(4)));
typedef float f32x4 __attribute__((ext_vector_type(4)));

__device__ __forceinline__ f32x4 zero4() { f32x4 v = {0.f, 0.f, 0.f, 0.f}; return v; }

// bare-instruction exp2: exactly 1 VALU issue (s_nop covers the trans-op wait state on SALU)
__device__ __forceinline__ float fexp2(float x) {
  float r;
  asm("v_exp_f32 %0, %1\n\ts_nop 0" : "=v"(r) : "v"(x));
  return r;
}

// 3-input max, 1 VALU issue
__device__ __forceinline__ float max3f(float a, float b, float c) {
  float r;
  asm("v_max3_f32 %0, %1, %2, %3" : "=v"(r) : "v"(a), "v"(b), "v"(c));
  return r;
}

// async global->LDS, 16B per lane; LDS base wave-uniform, HW adds lane*16
__device__ __forceinline__ void g2l16(const void* g, void* l) {
  __builtin_amdgcn_global_load_lds(
      (const __attribute__((address_space(1))) void*)g,
      (__attribute__((address_space(3))) void*)l, 16, 0, 0);
}

// ---------------- fused prep: x cast (blocks 0..4095) + Wqkv transpose (4096..4863)
// ---------------- + Wout transpose (4864..5119). Branch is block-uniform.
__global__ __launch_bounds__(256) void prep(const float* __restrict__ x,
                                            const float* __restrict__ Wqkv,
                                            const float* __restrict__ Wout,
                                            bf16* __restrict__ xb,
                                            bf16* __restrict__ WqkvT,
                                            bf16* __restrict__ WoutT) {
  __shared__ alignas(16) bf16 ts[64 * 65];
  const int id = blockIdx.x;
  const int tid = threadIdx.x;
  if (id < 4096) {   // ---- cast fp32 -> bf16, 8 elems/thread ----
    const size_t i = ((size_t)id * 256 + tid) * 8;
    float4 a = *(const float4*)(x + i);
    float4 b = *(const float4*)(x + i + 4);
    bf16x8 v;
    v[0] = (bf16)a.x; v[1] = (bf16)a.y; v[2] = (bf16)a.z; v[3] = (bf16)a.w;
    v[4] = (bf16)b.x; v[5] = (bf16)b.y; v[6] = (bf16)b.z; v[7] = (bf16)b.w;
    *(bf16x8*)(xb + i) = v;
    return;
  }
  // ---- weight transpose + cast: dst[C][R] = (bf16)src[R][C], R = D_ ----
  const float* src; bf16* dst; int C, t;
  if (id < 4096 + 768) { t = id - 4096; src = Wqkv; dst = WqkvT; C = 3 * D_; }
  else                 { t = id - 4864; src = Wout; dst = WoutT; C = D_; }
  const int r0 = (t & 15) * 64, c0 = (t >> 4) * 64;
  {
    int rr = tid >> 2, cc = (tid & 3) * 16;
    const float4* p4 = (const float4*)(src + (size_t)(r0 + rr) * C + c0 + cc);
    float fv[16];
#pragma unroll
    for (int q = 0; q < 4; ++q) *(float4*)&fv[q * 4] = p4[q];
#pragma unroll
    for (int i = 0; i < 16; ++i) ts[(cc + i) * 65 + rr] = (bf16)fv[i];
  }
  __syncthreads();
  {
    int rr = tid >> 2, cc = (tid & 3) * 16;
    bf16x8 a, b;
#pragma unroll
    for (int i = 0; i < 8; ++i) a[i] = ts[rr * 65 + cc + i];
#pragma unroll
    for (int i = 0; i < 8; ++i) b[i] = ts[rr * 65 + cc + 8 + i];
    bf16* q = dst + (size_t)(c0 + rr) * D_ + r0 + cc;
    *(bf16x8*)q = a;
    *(bf16x8*)(q + 8) = b;
  }
}

// ---------------- GEMM, 2-phase double-buffered (T3-min): BK=32 ----------------
// Per iter: stage(next buf) -> ds_read(cur)+MFMA -> ONE barrier (drains prefetch
// vmcnt(0) + readers of cur). Loads in flight across a full compute phase -- the
// old single-buffer loop exposed staging latency every K-step.
// Swizzle: LDS dest linear (rule 21); source chunk c ^= (row>>1)&3; read chunk
// quad ^ (l16>>1)&3 -> uniform 8 lanes / 4-bank slot = b128 floor, conflict-free.
// K-chunk accumulation order identical to BK=64 version -> bit-identical output.
template <bool FUSE>
__global__ __launch_bounds__(256) void gemm64(const bf16* __restrict__ A,
                                              const bf16* __restrict__ Bt,
                                              const float* __restrict__ bias,
                                              bf16* __restrict__ Cbf,
                                              float* __restrict__ Cf,
                                              const float* __restrict__ resid,
                                              int N, int K, int lda, int ldc) {
  __shared__ alignas(16) bf16 As[2][128 * 32];
  __shared__ alignas(16) bf16 Bs[2][128 * 32];
  const int tid = threadIdx.x;
  const int wid = tid >> 6, lane = tid & 63, quad = lane >> 4, l16 = lane & 15;
  const int m0 = blockIdx.x * 128, n0 = blockIdx.y * 128;
  const int wr = (wid >> 1) * 64, wc = (wid & 1) * 64;
  const int rsw = (l16 >> 1) & 3;   // read-side swizzle ((row>>1)&3 of fragment rows)

  f32x4 acc[4][4];
#pragma unroll
  for (int i = 0; i < 4; ++i)
#pragma unroll
    for (int j = 0; j < 4; ++j) acc[i][j] = zero4();

  // stage one 128x32 K-slab of A and B into buffer buf (linear LDS dest)
  auto stage = [&](int buf, int k0) {
#pragma unroll
    for (int p = 0; p < 2; ++p) {
      const int t = p * 256 + tid;
      const int row = t >> 2;
      const int kcs = ((t & 3) ^ ((row >> 1) & 3)) * 8;   // pre-swizzled source chunk
      g2l16(Bt + (size_t)(n0 + row) * K + k0 + kcs, (char*)&Bs[buf][0] + p * 4096 + wid * 1024);
      g2l16(A + (size_t)(m0 + row) * lda + k0 + kcs, (char*)&As[buf][0] + p * 4096 + wid * 1024);
    }
  };

  stage(0, 0);
  __syncthreads();   // vmcnt(0) drain -> slab 0 staged

  const int nk = K >> 5;
  for (int kt = 0; kt < nk; ++kt) {
    const int cur = kt & 1;
    if (kt + 1 < nk) stage(cur ^ 1, (kt + 1) * 32);   // in flight during compute

    bf16x8 af[4], bfr[4];
#pragma unroll
    for (int i = 0; i < 4; ++i)
      af[i] = *(const bf16x8*)&As[cur][(wr + i * 16 + l16) * 32 + ((quad ^ rsw) * 8)];
#pragma unroll
    for (int j = 0; j < 4; ++j)
      bfr[j] = *(const bf16x8*)&Bs[cur][(wc + j * 16 + l16) * 32 + ((quad ^ rsw) * 8)];
#pragma unroll
    for (int i = 0; i < 4; ++i)
#pragma unroll
      for (int j = 0; j < 4; ++j)
        acc[i][j] = __builtin_amdgcn_mfma_f32_16x16x32_bf16(af[i], bfr[j], acc[i][j], 0, 0, 0);

    __syncthreads();   // drains this iter's prefetch + all waves done reading cur
  }

#pragma unroll
  for (int i = 0; i < 4; ++i) {
#pragma unroll
    for (int j = 0; j < 4; ++j) {
      const int col = n0 + wc + j * 16 + l16;
      const float bv = bias[col];
#pragma unroll
      for (int r = 0; r < 4; ++r) {
        const int row = m0 + wr + i * 16 + quad * 4 + r;
        const float v = acc[i][j][r] + bv;
        if (FUSE) {
          const size_t off = (size_t)row * N + col;
          Cf[off] = v + resid[off];
        } else {
          Cbf[(size_t)row * ldc + col] = (bf16)v;
        }
      }
    }
  }
}

// ---------------- flash attention: block = (b, h, 128 q-rows), 4 waves x 32 rows ----------------
// T15 QK-ahead pipeline (R10/R11, unchanged): iteration t = softmax(t) [VALU] ->
// QK^T(t+1) [MFMA, independent] -> PV(t) [MFMA]. K staged 2 ahead (3 buffers), V 1
// ahead (2): 40 KB LDS, 4 blocks/CU. Buffer safety: every buffer overwritten in
// iter t was last read >= 2 barriers ago; barriers carry vmcnt(0) drain.
__global__ __launch_bounds__(256, 4) void attn_db(const bf16* __restrict__ qkv,
                                                  bf16* __restrict__ ao) {
  __shared__ alignas(16) bf16 Ks[3][4096];   // [buf][key][f-chunk swz], row = 128 B
  __shared__ alignas(16) bf16 Vs2[2][4096];  // [buf][key4][fg][4][16] subtiled for tr_read
  const int tid = threadIdx.x;
  const int wid = tid >> 6, lane = tid & 63, quad = lane >> 4, l16 = lane & 15;
  // XCD swizzle (attn keeps it: 16 q-blocks share one (b,h) K/V panel -> L2 reuse,
  // proven by R6's FETCH_SIZE 139->18.5 MB)
  const int bid0 = blockIdx.x;
  const int bid = ((bid0 & 7) << 7) | (bid0 >> 3);
  const int qb = bid & 15, h = (bid >> 4) & 15, b = bid >> 8;
  const int q0 = qb * 128;

  // K staging: lane covers (row = lane>>3, 16B chunk = lane&7), source chunk
  // pre-swizzled by row&7 so LDS stays linear (rule-21 involution).
  const int lrow8 = lane >> 3;
  const int kch = (lane & 7) ^ lrow8;
  const bf16* kg = qkv + (size_t)(b * T_ + wid * 16 + lrow8) * (3 * D_) + D_ + h * DK_ + kch * 8;
  // V staging: wave wid fills key4 slots {wid*2+(lane>>5)} (+8 for issue 2), i.e.
  // tokens wid*8 + (lane>>5)*4 + ((lane>>1)&3); f chunk ((lane>>3)&3)*16+(lane&1)*8.
  const int vtok = wid * 8 + (lane >> 5) * 4 + ((lane >> 1) & 3);
  const int vfof = ((lane >> 3) & 3) * 16 + (lane & 1) * 8;
  const bf16* vg = qkv + (size_t)(b * T_ + vtok) * (3 * D_) + 2 * D_ + h * DK_ + vfof;
  const unsigned vbase = (unsigned)(uintptr_t)&Vs2[0][0];

  // Q as MFMA B-operand (k=quad*8+j, n=qrow=l16), pre-scaled by log2e/8
  const float SC = 0.125f * 1.44269504f;
  bf16x8 qA[2], qB[2];
  {
    const bf16* qpA = qkv + (size_t)(b * T_ + q0 + wid * 32 + l16) * (3 * D_) + h * DK_ + quad * 8;
    const bf16* qpB = qpA + (size_t)16 * (3 * D_);
    qA[0] = *(const bf16x8*)qpA;       qA[1] = *(const bf16x8*)(qpA + 32);
    qB[0] = *(const bf16x8*)qpB;       qB[1] = *(const bf16x8*)(qpB + 32);
#pragma unroll
    for (int i = 0; i < 8; ++i) {
      qA[0][i] = (bf16)((float)qA[0][i] * SC); qA[1][i] = (bf16)((float)qA[1][i] * SC);
      qB[0][i] = (bf16)((float)qB[0][i] * SC); qB[1][i] = (bf16)((float)qB[1][i] * SC);
    }
  }

  float miA = -1e30f, miB = -1e30f;     // row-uniform (qrow = l16)
  f32x4 liA4 = zero4(), liB4 = zero4(); // per-lane partial sums (row l16)
  f32x4 oA[4], oB[4];                   // o[ft][r] = O[qrow=quad*4+r][f=ft*16+l16]
#pragma unroll
  for (int ft = 0; ft < 4; ++ft) { oA[ft] = zero4(); oB[ft] = zero4(); }

  auto stageK = [&](int kb, int t0) {
    g2l16(kg + (size_t)(t0 + 0) * (3 * D_), &Ks[kb][(wid * 16 + 0) * 64]);
    g2l16(kg + (size_t)(t0 + 8) * (3 * D_), &Ks[kb][(wid * 16 + 8) * 64]);
  };
  auto stageV = [&](int vb, int t0) {
    g2l16(vg + (size_t)(t0 + 0) * (3 * D_),  (char*)&Vs2[vb][0] + (0 + wid * 2) * 512);
    g2l16(vg + (size_t)(t0 + 32) * (3 * D_), (char*)&Vs2[vb][0] + (8 + wid * 2) * 512);
  };

  f32x4 svA[4], svB[4];
  auto qk = [&](const bf16* Kb) {
#pragma unroll
    for (int nt = 0; nt < 4; ++nt) { svA[nt] = zero4(); svB[nt] = zero4(); }
    __builtin_amdgcn_s_setprio(1);
#pragma unroll
    for (int nt = 0; nt < 4; ++nt)
#pragma unroll
      for (int ks = 0; ks < 2; ++ks) {
        const bf16x8 kf = *(const bf16x8*)
            &Kb[(nt * 16 + l16) * 64 + (((ks << 2) | quad) ^ (l16 & 7)) * 8];
        svA[nt] = __builtin_amdgcn_mfma_f32_16x16x32_bf16(kf, qA[ks], svA[nt], 0, 0, 0);
        svB[nt] = __builtin_amdgcn_mfma_f32_16x16x32_bf16(kf, qB[ks], svB[nt], 0, 0, 0);
      }
    __builtin_amdgcn_s_setprio(0);
  };

  // prologue: stage tiles 0 (K+V) and 1 (K); compute QK(0)
  stageK(0, 0); stageV(0, 0);
  stageK(1, 64);
  __syncthreads();           // vmcnt(0) drain -> tiles staged
  qk(&Ks[0][0]);             // sv(0)

  const int NT = T_ / 64;
  int kbQ = 1, kbS = 2;      // kbQ = (kt+1)%3 (QK-ahead read), kbS = (kt+2)%3 (stage)
  for (int kt = 0; kt < NT; ++kt) {
    if (kt + 2 < NT) stageK(kbS, (kt + 2) * 64);        // in flight during compute
    if (kt + 1 < NT) stageV((kt + 1) & 1, (kt + 1) * 64);

    // ---- softmax(kt) on sv (VALU) ----
    // per-lane LOCAL max via max3 chains (16 scores per half) -- no cross-lane reduce
    float a0 = max3f(svA[0][0], svA[0][1], svA[0][2]);
    float a1 = max3f(svA[0][3], svA[1][0], svA[1][1]);
    a0 = max3f(a0, svA[1][2], svA[1][3]);
    a1 = max3f(a1, svA[2][0], svA[2][1]);
    a0 = max3f(a0, svA[2][2], svA[2][3]);
    a1 = max3f(a1, svA[3][0], svA[3][1]);
    a0 = max3f(a0, svA[3][2], svA[3][3]);
    float b0 = max3f(svB[0][0], svB[0][1], svB[0][2]);
    float b1 = max3f(svB[0][3], svB[1][0], svB[1][1]);
    b0 = max3f(b0, svB[1][2], svB[1][3]);
    b1 = max3f(b1, svB[2][0], svB[2][1]);
    b0 = max3f(b0, svB[2][2], svB[2][3]);
    b1 = max3f(b1, svB[3][0], svB[3][1]);
    b0 = max3f(b0, svB[3][2], svB[3][3]);
    const float tAl = fmaxf(a0, a1), tBl = fmaxf(b0, b1);

    // defer-max (T13): vote on local max; full row reduce only when triggered (rare)
    if (!__all(tAl <= miA + 8.f)) {
      float tA = fmaxf(tAl, __shfl_xor(tAl, 16, 64));
      tA = fmaxf(tA, __shfl_xor(tA, 32, 64));
      const float nm = fmaxf(miA, tA);
      const float al = fexp2(miA - nm);   // row-uniform for row l16
      miA = nm; liA4 *= al;
#pragma unroll
      for (int r = 0; r < 4; ++r) {
        const float ar = __shfl(al, quad * 4 + r, 64);
#pragma unroll
        for (int ft = 0; ft < 4; ++ft) oA[ft][r] *= ar;
      }
    }
    if (!__all(tBl <= miB + 8.f)) {
      float tB = fmaxf(tBl, __shfl_xor(tBl, 16, 64));
      tB = fmaxf(tB, __shfl_xor(tB, 32, 64));
      const float nm = fmaxf(miB, tB);
      const float al = fexp2(miB - nm);
      miB = nm; liB4 *= al;
#pragma unroll
      for (int r = 0; r < 4; ++r) {
        const float ar = __shfl(al, quad * 4 + r, 64);
#pragma unroll
        for (int ft = 0; ft < 4; ++ft) oB[ft][r] *= ar;
      }
    }

    // P = exp2(S - mi); accumulate per-lane li partials; pack to bf16 (frees sv)
    s16x4 pA[4], pB[4];
#pragma unroll
    for (int nt = 0; nt < 4; ++nt) {
      f32x4 dA = svA[nt] - miA;
      dA[0] = fexp2(dA[0]); dA[1] = fexp2(dA[1]); dA[2] = fexp2(dA[2]); dA[3] = fexp2(dA[3]);
      liA4 += dA;
      union { bf16x4 b; s16x4 s; } ua;
#pragma unroll
      for (int j = 0; j < 4; ++j) ua.b[j] = (bf16)dA[j];
      pA[nt] = ua.s;
      f32x4 dB = svB[nt] - miB;
      dB[0] = fexp2(dB[0]); dB[1] = fexp2(dB[1]); dB[2] = fexp2(dB[2]); dB[3] = fexp2(dB[3]);
      liB4 += dB;
      union { bf16x4 b; s16x4 s; } ub;
#pragma unroll
      for (int j = 0; j < 4; ++j) ub.b[j] = (bf16)dB[j];
      pB[nt] = ub.s;
    }

    // ---- QK^T(kt+1) (MFMA, independent of softmax above -> co-issues) ----
    if (kt + 1 < NT) qk(&Ks[kbQ][0]);

    // ---- PV(kt): vf via HW transpose read (T10) from subtiled Vs2[kt&1] ----
    // Group quad reads block (key4=ks*4+quad, fg=ft): delivered elem j =
    // V[ks*16+quad*4+j][ft*16+l16] == the PV B-operand exactly.
    __builtin_amdgcn_s_setprio(1);
    {
      const unsigned va = vbase + (unsigned)(kt & 1) * 8192u + (unsigned)(quad * 512 + l16 * 8);
#pragma unroll
      for (int ks = 0; ks < 4; ++ks) {
        s16x4 vf[4];
#pragma unroll
        for (int ft = 0; ft < 4; ++ft)
          asm volatile("ds_read_b64_tr_b16 %0, %1 offset:%2"
                       : "=v"(vf[ft]) : "v"(va), "i"(ks * 2048 + ft * 128));
        asm volatile("s_waitcnt lgkmcnt(0)" ::: "memory");
        __builtin_amdgcn_sched_barrier(0);   // rule 18: keep MFMAs after the wait
#pragma unroll
        for (int ft = 0; ft < 4; ++ft) {
          oA[ft] = __builtin_amdgcn_mfma_f32_16x16x16bf16_1k(pA[ks], vf[ft], oA[ft], 0, 0, 0);
          oB[ft] = __builtin_amdgcn_mfma_f32_16x16x16bf16_1k(pB[ks], vf[ft], oB[ft], 0, 0, 0);
        }
      }
    }
    __builtin_amdgcn_s_setprio(0);

    __syncthreads();   // drains this iter's prefetch (vmcnt 0) + all waves done reading
    const int old = 3 - kbQ - kbS;   // buffers cycle {0,1,2}
    kbQ = kbS; kbS = old;
  }

  // epilogue: fold li partials (once): horizontal + cross-quad for row l16
  float sA = (liA4[0] + liA4[1]) + (liA4[2] + liA4[3]);
  sA += __shfl_xor(sA, 16, 64);
  sA += __shfl_xor(sA, 32, 64);
  float sB = (liB4[0] + liB4[1]) + (liB4[2] + liB4[3]);
  sB += __shfl_xor(sB, 16, 64);
  sB += __shfl_xor(sB, 32, 64);

  // normalize rows (sum for qrow=quad*4+r lives at lane quad*4+r); dense [M][D] out
#pragma unroll
  for (int r = 0; r < 4; ++r) {
    const float invA = 1.0f / __shfl(sA, quad * 4 + r, 64);
    const float invB = 1.0f / __shfl(sB, quad * 4 + r, 64);
    const int rowA = b * T_ + q0 + wid * 32 + quad * 4 + r;
    const int rowB = rowA + 16;
#pragma unroll
    for (int ft = 0; ft < 4; ++ft) {
      ao[(size_t)rowA * D_ + h * DK_ + ft * 16 + l16] = (bf16)(oA[ft][r] * invA);
      ao[(size_t)rowB * D_ + h * DK_ + ft * 16 + l16] = (bf16)(oB[ft][r] * invB);
    }
  }
}

// ---------------- layernorm: one wave per row, in-place, no LDS/barrier ----------------
__global__ __launch_bounds__(256) void ln_out(float* __restrict__ res,
                                              const float* __restrict__ gamma,
                                              const float* __restrict__ beta) {
  const int row = blockIdx.x * 4 + (threadIdx.x >> 6);
  const int lane = threadIdx.x & 63;
  float4 v[4];
  float s = 0.f, q = 0.f;
#pragma unroll
  for (int p = 0; p < 4; ++p) {
    v[p] = *(const float4*)(res + (size_t)row * D_ + p * 256 + lane * 4);
    s += v[p].x + v[p].y + v[p].z + v[p].w;
    q += v[p].x * v[p].x + v[p].y * v[p].y + v[p].z * v[p].z + v[p].w * v[p].w;
  }
#pragma unroll
  for (int m = 1; m < 64; m <<= 1) { s += __shfl_xor(s, m, 64); q += __shfl_xor(q, m, 64); }
  const float mu = s * (1.0f / D_);
  const float var = q * (1.0f / D_) - mu * mu;
  const float rstd = rsqrtf(var + 1e-5f);
#pragma unroll
  for (int p = 0; p < 4; ++p) {
    const int c = p * 256 + lane * 4;
    const float4 g = *(const float4*)(gamma + c);
    const float4 be = *(const float4*)(beta + c);
    float4 ov;
    ov.x = (v[p].x - mu) * rstd * g.x + be.x;
    ov.y = (v[p].y - mu) * rstd * g.y + be.y;
    ov.z = (v[p].z - mu) * rstd * g.z + be.z;
    ov.w = (v[p].w - mu) * rstd * g.w + be.w;
    *(float4*)(res + (size_t)row * D_ + c) = ov;
  }
}

extern "C" void kernel_launch(void* const* d_in, const int* in_sizes, int n_in,
                              void* d_out, int out_size, void* d_ws, size_t ws_size,
                              hipStream_t stream) {
  const float* x     = (const float*)d_in[0];
  const float* Wqkv  = (const float*)d_in[1];
  const float* bqkv  = (const float*)d_in[2];
  const float* Wout  = (const float*)d_in[3];
  const float* bout  = (const float*)d_in[4];
  const float* gamma = (const float*)d_in[5];
  const float* beta  = (const float*)d_in[6];
  float* out = (float*)d_out;  // fp32 residual buffer too (LN in-place)

  // workspace layout (75.5 MB footprint unchanged):
  char* ws = (char*)d_ws;
  bf16* WqkvT = (bf16*)ws; ws += (size_t)3 * D_ * D_ * 2;        // [3072][1024]
  bf16* WoutT = (bf16*)ws; ws += (size_t)D_ * D_ * 2;            // [1024][1024]
  bf16* qkv   = (bf16*)ws; ws += (size_t)M_ * 3 * D_ * 2;        // [8192][3072]
  bf16* ao    = (bf16*)ws;                                       // [8192][1024] attn out
  bf16* xb    = ao;            // x in bf16 time-shares the slot (dead after QKV gemm)

  prep<<<4096 + 768 + 256, 256, 0, stream>>>(x, Wqkv, Wout, xb, WqkvT, WoutT);
  gemm64<false><<<dim3(M_ / 128, 3 * D_ / 128), 256, 0, stream>>>(
      xb, WqkvT, bqkv, qkv, nullptr, nullptr, 3 * D_, D_, D_, 3 * D_);
  attn_db<<<B_ * H_ * (T_ / 128), 256, 0, stream>>>(qkv, ao);
  gemm64<true><<<dim3(M_ / 128, D_ / 128), 256, 0, stream>>>(
      ao, WoutT, bout, nullptr, out, x, D_, D_, D_, D_);
  ln_out<<<M_ / 4, 256, 0, stream>>>(out, gamma, beta);
}

// Round 15
// 284.790 us; speedup vs baseline: 1.0804x; 1.0804x over previous
//
#include <hip/hip_runtime.h>

#define B_ 4
#define T_ 2048
#define D_ 1024
#define H_ 16
#define DK_ 64
#define M_ (B_*T_)   // 8192 rows

typedef __bf16 bf16;
typedef __bf16 bf16x8 __attribute__((ext_vector_type(8)));
typedef __bf16 bf16x4 __attribute__((ext_vector_type(4)));
typedef short s16x4 __attribute__((ext_vector_type(4)));
typedef float f32x4 __attribute__((ext_vector_type(4)));

__device__ __forceinline__ f32x4 zero4() { f32x4 v = {0.f, 0.f, 0.f, 0.f}; return v; }

// bare-instruction exp2: exactly 1 VALU issue (s_nop covers the trans-op wait state on SALU)
__device__ __forceinline__ float fexp2(float x) {
  float r;
  asm("v_exp_f32 %0, %1\n\ts_nop 0" : "=v"(r) : "v"(x));
  return r;
}

// 3-input max, 1 VALU issue
__device__ __forceinline__ float max3f(float a, float b, float c) {
  float r;
  asm("v_max3_f32 %0, %1, %2, %3" : "=v"(r) : "v"(a), "v"(b), "v"(c));
  return r;
}

// async global->LDS, 16B per lane; LDS base wave-uniform, HW adds lane*16
__device__ __forceinline__ void g2l16(const void* g, void* l) {
  __builtin_amdgcn_global_load_lds(
      (const __attribute__((address_space(1))) void*)g,
      (__attribute__((address_space(3))) void*)l, 16, 0, 0);
}

// ---------------- fused prep: x cast (blocks 0..4095) + Wqkv transpose (4096..4863)
// ---------------- + Wout transpose (4864..5119). Branch is block-uniform.
__global__ __launch_bounds__(256) void prep(const float* __restrict__ x,
                                            const float* __restrict__ Wqkv,
                                            const float* __restrict__ Wout,
                                            bf16* __restrict__ xb,
                                            bf16* __restrict__ WqkvT,
                                            bf16* __restrict__ WoutT) {
  __shared__ alignas(16) bf16 ts[64 * 65];
  const int id = blockIdx.x;
  const int tid = threadIdx.x;
  if (id < 4096) {   // ---- cast fp32 -> bf16, 8 elems/thread ----
    const size_t i = ((size_t)id * 256 + tid) * 8;
    float4 a = *(const float4*)(x + i);
    float4 b = *(const float4*)(x + i + 4);
    bf16x8 v;
    v[0] = (bf16)a.x; v[1] = (bf16)a.y; v[2] = (bf16)a.z; v[3] = (bf16)a.w;
    v[4] = (bf16)b.x; v[5] = (bf16)b.y; v[6] = (bf16)b.z; v[7] = (bf16)b.w;
    *(bf16x8*)(xb + i) = v;
    return;
  }
  // ---- weight transpose + cast: dst[C][R] = (bf16)src[R][C], R = D_ ----
  const float* src; bf16* dst; int C, t;
  if (id < 4096 + 768) { t = id - 4096; src = Wqkv; dst = WqkvT; C = 3 * D_; }
  else                 { t = id - 4864; src = Wout; dst = WoutT; C = D_; }
  const int r0 = (t & 15) * 64, c0 = (t >> 4) * 64;
  {
    int rr = tid >> 2, cc = (tid & 3) * 16;
    const float4* p4 = (const float4*)(src + (size_t)(r0 + rr) * C + c0 + cc);
    float fv[16];
#pragma unroll
    for (int q = 0; q < 4; ++q) *(float4*)&fv[q * 4] = p4[q];
#pragma unroll
    for (int i = 0; i < 16; ++i) ts[(cc + i) * 65 + rr] = (bf16)fv[i];
  }
  __syncthreads();
  {
    int rr = tid >> 2, cc = (tid & 3) * 16;
    bf16x8 a, b;
#pragma unroll
    for (int i = 0; i < 8; ++i) a[i] = ts[rr * 65 + cc + i];
#pragma unroll
    for (int i = 0; i < 8; ++i) b[i] = ts[rr * 65 + cc + 8 + i];
    bf16* q = dst + (size_t)(c0 + rr) * D_ + r0 + cc;
    *(bf16x8*)q = a;
    *(bf16x8*)(q + 8) = b;
  }
}

// ---------------- GEMM BK=64: C[M][N] = A[M][K] @ Bt[N][K]^T + bias ----------------
// 2D grid (no XCD swizzle: operands are L3-fit; swizzle measured -2%). Staging:
// linear global_load_lds dest + source chunk pre-swizzled by row&7 + read chunk
// ^= l16&7 (rule-21 involution). Single-buffer: explicit dbuf measured null-to-
// negative (R14, reproducing m99/m100) -- cross-block TLP covers staging latency.
// Scalar-store epilogue: packed variant measured -17us (R12; 16 rows/quad per
// packed store scatters worse than 32B-contiguous scalar pattern).
template <bool FUSE>
__global__ __launch_bounds__(256) void gemm64(const bf16* __restrict__ A,
                                              const bf16* __restrict__ Bt,
                                              const float* __restrict__ bias,
                                              bf16* __restrict__ Cbf,
                                              float* __restrict__ Cf,
                                              const float* __restrict__ resid,
                                              int N, int K, int lda, int ldc) {
  __shared__ alignas(16) bf16 As[128 * 64];
  __shared__ alignas(16) bf16 Bs[128 * 64];
  const int tid = threadIdx.x;
  const int wid = tid >> 6, lane = tid & 63, quad = lane >> 4, l16 = lane & 15;
  const int m0 = blockIdx.x * 128, n0 = blockIdx.y * 128;
  const int wr = (wid >> 1) * 64, wc = (wid & 1) * 64;
  const int sw = l16 & 7;   // read-side swizzle (row&7 of every fragment row)

  f32x4 acc[4][4];
#pragma unroll
  for (int i = 0; i < 4; ++i)
#pragma unroll
    for (int j = 0; j < 4; ++j) acc[i][j] = zero4();

  for (int k0 = 0; k0 < K; k0 += 64) {
    __syncthreads();  // previous iteration's LDS reads complete
#pragma unroll
    for (int p = 0; p < 4; ++p) {
      const int t = p * 256 + tid;
      const int row = t >> 3;
      const int kcs = ((t & 7) ^ (row & 7)) * 8;   // pre-swizzled source chunk
      g2l16(Bt + (size_t)(n0 + row) * K + k0 + kcs, (char*)Bs + p * 4096 + wid * 1024);
      g2l16(A + (size_t)(m0 + row) * lda + k0 + kcs, (char*)As + p * 4096 + wid * 1024);
    }
    __syncthreads();
#pragma unroll
    for (int kk = 0; kk < 2; ++kk) {
      bf16x8 af[4], bfr[4];
#pragma unroll
      for (int i = 0; i < 4; ++i)
        af[i] = *(const bf16x8*)&As[(wr + i * 16 + l16) * 64 + ((((kk << 2) | quad) ^ sw) * 8)];
#pragma unroll
      for (int j = 0; j < 4; ++j)
        bfr[j] = *(const bf16x8*)&Bs[(wc + j * 16 + l16) * 64 + ((((kk << 2) | quad) ^ sw) * 8)];
#pragma unroll
      for (int i = 0; i < 4; ++i)
#pragma unroll
        for (int j = 0; j < 4; ++j)
          acc[i][j] = __builtin_amdgcn_mfma_f32_16x16x32_bf16(af[i], bfr[j], acc[i][j], 0, 0, 0);
    }
  }

#pragma unroll
  for (int i = 0; i < 4; ++i) {
#pragma unroll
    for (int j = 0; j < 4; ++j) {
      const int col = n0 + wc + j * 16 + l16;
      const float bv = bias[col];
#pragma unroll
      for (int r = 0; r < 4; ++r) {
        const int row = m0 + wr + i * 16 + quad * 4 + r;
        const float v = acc[i][j][r] + bv;
        if (FUSE) {
          const size_t off = (size_t)row * N + col;
          Cf[off] = v + resid[off];
        } else {
          Cbf[(size_t)row * ldc + col] = (bf16)v;
        }
      }
    }
  }
}

// ---------------- flash attention: block = (b, h, 128 q-rows), 4 waves x 32 rows ----------------
// T15 QK-ahead pipeline: iteration t = softmax(t) [VALU] -> QK^T(t+1) [MFMA,
// independent] -> PV(t) [MFMA]. K staged 2 ahead (3 buffers), V 1 ahead (2):
// 40 KB LDS, 4 blocks/CU. Buffer safety: every buffer overwritten in iter t was
// last read >= 2 barriers ago; barriers carry vmcnt(0) drain.
__global__ __launch_bounds__(256, 4) void attn_db(const bf16* __restrict__ qkv,
                                                  bf16* __restrict__ ao) {
  __shared__ alignas(16) bf16 Ks[3][4096];   // [buf][key][f-chunk swz], row = 128 B
  __shared__ alignas(16) bf16 Vs2[2][4096];  // [buf][key4][fg][4][16] subtiled for tr_read
  const int tid = threadIdx.x;
  const int wid = tid >> 6, lane = tid & 63, quad = lane >> 4, l16 = lane & 15;
  // XCD swizzle (attn keeps it: 16 q-blocks share one (b,h) K/V panel -> L2 reuse,
  // proven by R6's FETCH_SIZE 139->18.5 MB)
  const int bid0 = blockIdx.x;
  const int bid = ((bid0 & 7) << 7) | (bid0 >> 3);
  const int qb = bid & 15, h = (bid >> 4) & 15, b = bid >> 8;
  const int q0 = qb * 128;

  // K staging: lane covers (row = lane>>3, 16B chunk = lane&7), source chunk
  // pre-swizzled by row&7 so LDS stays linear (rule-21 involution).
  const int lrow8 = lane >> 3;
  const int kch = (lane & 7) ^ lrow8;
  const bf16* kg = qkv + (size_t)(b * T_ + wid * 16 + lrow8) * (3 * D_) + D_ + h * DK_ + kch * 8;
  // V staging: wave wid fills key4 slots {wid*2+(lane>>5)} (+8 for issue 2), i.e.
  // tokens wid*8 + (lane>>5)*4 + ((lane>>1)&3); f chunk ((lane>>3)&3)*16+(lane&1)*8.
  const int vtok = wid * 8 + (lane >> 5) * 4 + ((lane >> 1) & 3);
  const int vfof = ((lane >> 3) & 3) * 16 + (lane & 1) * 8;
  const bf16* vg = qkv + (size_t)(b * T_ + vtok) * (3 * D_) + 2 * D_ + h * DK_ + vfof;
  const unsigned vbase = (unsigned)(uintptr_t)&Vs2[0][0];

  // Q as MFMA B-operand (k=quad*8+j, n=qrow=l16), pre-scaled by log2e/8
  const float SC = 0.125f * 1.44269504f;
  bf16x8 qA[2], qB[2];
  {
    const bf16* qpA = qkv + (size_t)(b * T_ + q0 + wid * 32 + l16) * (3 * D_) + h * DK_ + quad * 8;
    const bf16* qpB = qpA + (size_t)16 * (3 * D_);
    qA[0] = *(const bf16x8*)qpA;       qA[1] = *(const bf16x8*)(qpA + 32);
    qB[0] = *(const bf16x8*)qpB;       qB[1] = *(const bf16x8*)(qpB + 32);
#pragma unroll
    for (int i = 0; i < 8; ++i) {
      qA[0][i] = (bf16)((float)qA[0][i] * SC); qA[1][i] = (bf16)((float)qA[1][i] * SC);
      qB[0][i] = (bf16)((float)qB[0][i] * SC); qB[1][i] = (bf16)((float)qB[1][i] * SC);
    }
  }

  float miA = -1e30f, miB = -1e30f;     // row-uniform (qrow = l16)
  f32x4 liA4 = zero4(), liB4 = zero4(); // per-lane partial sums (row l16)
  f32x4 oA[4], oB[4];                   // o[ft][r] = O[qrow=quad*4+r][f=ft*16+l16]
#pragma unroll
  for (int ft = 0; ft < 4; ++ft) { oA[ft] = zero4(); oB[ft] = zero4(); }

  auto stageK = [&](int kb, int t0) {
    g2l16(kg + (size_t)(t0 + 0) * (3 * D_), &Ks[kb][(wid * 16 + 0) * 64]);
    g2l16(kg + (size_t)(t0 + 8) * (3 * D_), &Ks[kb][(wid * 16 + 8) * 64]);
  };
  auto stageV = [&](int vb, int t0) {
    g2l16(vg + (size_t)(t0 + 0) * (3 * D_),  (char*)&Vs2[vb][0] + (0 + wid * 2) * 512);
    g2l16(vg + (size_t)(t0 + 32) * (3 * D_), (char*)&Vs2[vb][0] + (8 + wid * 2) * 512);
  };

  f32x4 svA[4], svB[4];
  auto qk = [&](const bf16* Kb) {
#pragma unroll
    for (int nt = 0; nt < 4; ++nt) { svA[nt] = zero4(); svB[nt] = zero4(); }
    __builtin_amdgcn_s_setprio(1);
#pragma unroll
    for (int nt = 0; nt < 4; ++nt)
#pragma unroll
      for (int ks = 0; ks < 2; ++ks) {
        const bf16x8 kf = *(const bf16x8*)
            &Kb[(nt * 16 + l16) * 64 + (((ks << 2) | quad) ^ (l16 & 7)) * 8];
        svA[nt] = __builtin_amdgcn_mfma_f32_16x16x32_bf16(kf, qA[ks], svA[nt], 0, 0, 0);
        svB[nt] = __builtin_amdgcn_mfma_f32_16x16x32_bf16(kf, qB[ks], svB[nt], 0, 0, 0);
      }
    __builtin_amdgcn_s_setprio(0);
  };

  // prologue: stage tiles 0 (K+V) and 1 (K); compute QK(0)
  stageK(0, 0); stageV(0, 0);
  stageK(1, 64);
  __syncthreads();           // vmcnt(0) drain -> tiles staged
  qk(&Ks[0][0]);             // sv(0)

  const int NT = T_ / 64;
  int kbQ = 1, kbS = 2;      // kbQ = (kt+1)%3 (QK-ahead read), kbS = (kt+2)%3 (stage)
  for (int kt = 0; kt < NT; ++kt) {
    if (kt + 2 < NT) stageK(kbS, (kt + 2) * 64);        // in flight during compute
    if (kt + 1 < NT) stageV((kt + 1) & 1, (kt + 1) * 64);

    // ---- softmax(kt) on sv (VALU) ----
    // per-lane LOCAL max via max3 chains (16 scores per half) -- no cross-lane reduce
    float a0 = max3f(svA[0][0], svA[0][1], svA[0][2]);
    float a1 = max3f(svA[0][3], svA[1][0], svA[1][1]);
    a0 = max3f(a0, svA[1][2], svA[1][3]);
    a1 = max3f(a1, svA[2][0], svA[2][1]);
    a0 = max3f(a0, svA[2][2], svA[2][3]);
    a1 = max3f(a1, svA[3][0], svA[3][1]);
    a0 = max3f(a0, svA[3][2], svA[3][3]);
    float b0 = max3f(svB[0][0], svB[0][1], svB[0][2]);
    float b1 = max3f(svB[0][3], svB[1][0], svB[1][1]);
    b0 = max3f(b0, svB[1][2], svB[1][3]);
    b1 = max3f(b1, svB[2][0], svB[2][1]);
    b0 = max3f(b0, svB[2][2], svB[2][3]);
    b1 = max3f(b1, svB[3][0], svB[3][1]);
    b0 = max3f(b0, svB[3][2], svB[3][3]);
    const float tAl = fmaxf(a0, a1), tBl = fmaxf(b0, b1);

    // defer-max (T13): vote on local max; full row reduce only when triggered (rare)
    if (!__all(tAl <= miA + 8.f)) {
      float tA = fmaxf(tAl, __shfl_xor(tAl, 16, 64));
      tA = fmaxf(tA, __shfl_xor(tA, 32, 64));
      const float nm = fmaxf(miA, tA);
      const float al = fexp2(miA - nm);   // row-uniform for row l16
      miA = nm; liA4 *= al;
#pragma unroll
      for (int r = 0; r < 4; ++r) {
        const float ar = __shfl(al, quad * 4 + r, 64);
#pragma unroll
        for (int ft = 0; ft < 4; ++ft) oA[ft][r] *= ar;
      }
    }
    if (!__all(tBl <= miB + 8.f)) {
      float tB = fmaxf(tBl, __shfl_xor(tBl, 16, 64));
      tB = fmaxf(tB, __shfl_xor(tB, 32, 64));
      const float nm = fmaxf(miB, tB);
      const float al = fexp2(miB - nm);
      miB = nm; liB4 *= al;
#pragma unroll
      for (int r = 0; r < 4; ++r) {
        const float ar = __shfl(al, quad * 4 + r, 64);
#pragma unroll
        for (int ft = 0; ft < 4; ++ft) oB[ft][r] *= ar;
      }
    }

    // P = exp2(S - mi); accumulate per-lane li partials; pack to bf16 (frees sv)
    s16x4 pA[4], pB[4];
#pragma unroll
    for (int nt = 0; nt < 4; ++nt) {
      f32x4 dA = svA[nt] - miA;
      dA[0] = fexp2(dA[0]); dA[1] = fexp2(dA[1]); dA[2] = fexp2(dA[2]); dA[3] = fexp2(dA[3]);
      liA4 += dA;
      union { bf16x4 b; s16x4 s; } ua;
#pragma unroll
      for (int j = 0; j < 4; ++j) ua.b[j] = (bf16)dA[j];
      pA[nt] = ua.s;
      f32x4 dB = svB[nt] - miB;
      dB[0] = fexp2(dB[0]); dB[1] = fexp2(dB[1]); dB[2] = fexp2(dB[2]); dB[3] = fexp2(dB[3]);
      liB4 += dB;
      union { bf16x4 b; s16x4 s; } ub;
#pragma unroll
      for (int j = 0; j < 4; ++j) ub.b[j] = (bf16)dB[j];
      pB[nt] = ub.s;
    }

    // ---- QK^T(kt+1) (MFMA, independent of softmax above -> co-issues) ----
    if (kt + 1 < NT) qk(&Ks[kbQ][0]);

    // ---- PV(kt): vf via HW transpose read (T10) from subtiled Vs2[kt&1] ----
    // Group quad reads block (key4=ks*4+quad, fg=ft): delivered elem j =
    // V[ks*16+quad*4+j][ft*16+l16] == the PV B-operand exactly.
    __builtin_amdgcn_s_setprio(1);
    {
      const unsigned va = vbase + (unsigned)(kt & 1) * 8192u + (unsigned)(quad * 512 + l16 * 8);
#pragma unroll
      for (int ks = 0; ks < 4; ++ks) {
        s16x4 vf[4];
#pragma unroll
        for (int ft = 0; ft < 4; ++ft)
          asm volatile("ds_read_b64_tr_b16 %0, %1 offset:%2"
                       : "=v"(vf[ft]) : "v"(va), "i"(ks * 2048 + ft * 128));
        asm volatile("s_waitcnt lgkmcnt(0)" ::: "memory");
        __builtin_amdgcn_sched_barrier(0);   // rule 18: keep MFMAs after the wait
#pragma unroll
        for (int ft = 0; ft < 4; ++ft) {
          oA[ft] = __builtin_amdgcn_mfma_f32_16x16x16bf16_1k(pA[ks], vf[ft], oA[ft], 0, 0, 0);
          oB[ft] = __builtin_amdgcn_mfma_f32_16x16x16bf16_1k(pB[ks], vf[ft], oB[ft], 0, 0, 0);
        }
      }
    }
    __builtin_amdgcn_s_setprio(0);

    __syncthreads();   // drains this iter's prefetch (vmcnt 0) + all waves done reading
    const int old = 3 - kbQ - kbS;   // buffers cycle {0,1,2}
    kbQ = kbS; kbS = old;
  }

  // epilogue: fold li partials (once): horizontal + cross-quad for row l16
  float sA = (liA4[0] + liA4[1]) + (liA4[2] + liA4[3]);
  sA += __shfl_xor(sA, 16, 64);
  sA += __shfl_xor(sA, 32, 64);
  float sB = (liB4[0] + liB4[1]) + (liB4[2] + liB4[3]);
  sB += __shfl_xor(sB, 16, 64);
  sB += __shfl_xor(sB, 32, 64);

  // normalize rows (sum for qrow=quad*4+r lives at lane quad*4+r); dense [M][D] out
#pragma unroll
  for (int r = 0; r < 4; ++r) {
    const float invA = 1.0f / __shfl(sA, quad * 4 + r, 64);
    const float invB = 1.0f / __shfl(sB, quad * 4 + r, 64);
    const int rowA = b * T_ + q0 + wid * 32 + quad * 4 + r;
    const int rowB = rowA + 16;
#pragma unroll
    for (int ft = 0; ft < 4; ++ft) {
      ao[(size_t)rowA * D_ + h * DK_ + ft * 16 + l16] = (bf16)(oA[ft][r] * invA);
      ao[(size_t)rowB * D_ + h * DK_ + ft * 16 + l16] = (bf16)(oB[ft][r] * invB);
    }
  }
}

// ---------------- layernorm: one wave per row, in-place, no LDS/barrier ----------------
__global__ __launch_bounds__(256) void ln_out(float* __restrict__ res,
                                              const float* __restrict__ gamma,
                                              const float* __restrict__ beta) {
  const int row = blockIdx.x * 4 + (threadIdx.x >> 6);
  const int lane = threadIdx.x & 63;
  float4 v[4];
  float s = 0.f, q = 0.f;
#pragma unroll
  for (int p = 0; p < 4; ++p) {
    v[p] = *(const float4*)(res + (size_t)row * D_ + p * 256 + lane * 4);
    s += v[p].x + v[p].y + v[p].z + v[p].w;
    q += v[p].x * v[p].x + v[p].y * v[p].y + v[p].z * v[p].z + v[p].w * v[p].w;
  }
#pragma unroll
  for (int m = 1; m < 64; m <<= 1) { s += __shfl_xor(s, m, 64); q += __shfl_xor(q, m, 64); }
  const float mu = s * (1.0f / D_);
  const float var = q * (1.0f / D_) - mu * mu;
  const float rstd = rsqrtf(var + 1e-5f);
#pragma unroll
  for (int p = 0; p < 4; ++p) {
    const int c = p * 256 + lane * 4;
    const float4 g = *(const float4*)(gamma + c);
    const float4 be = *(const float4*)(beta + c);
    float4 ov;
    ov.x = (v[p].x - mu) * rstd * g.x + be.x;
    ov.y = (v[p].y - mu) * rstd * g.y + be.y;
    ov.z = (v[p].z - mu) * rstd * g.z + be.z;
    ov.w = (v[p].w - mu) * rstd * g.w + be.w;
    *(float4*)(res + (size_t)row * D_ + c) = ov;
  }
}

extern "C" void kernel_launch(void* const* d_in, const int* in_sizes, int n_in,
                              void* d_out, int out_size, void* d_ws, size_t ws_size,
                              hipStream_t stream) {
  const float* x     = (const float*)d_in[0];
  const float* Wqkv  = (const float*)d_in[1];
  const float* bqkv  = (const float*)d_in[2];
  const float* Wout  = (const float*)d_in[3];
  const float* bout  = (const float*)d_in[4];
  const float* gamma = (const float*)d_in[5];
  const float* beta  = (const float*)d_in[6];
  float* out = (float*)d_out;  // fp32 residual buffer too (LN in-place)

  // workspace layout (75.5 MB footprint unchanged):
  char* ws = (char*)d_ws;
  bf16* WqkvT = (bf16*)ws; ws += (size_t)3 * D_ * D_ * 2;        // [3072][1024]
  bf16* WoutT = (bf16*)ws; ws += (size_t)D_ * D_ * 2;            // [1024][1024]
  bf16* qkv   = (bf16*)ws; ws += (size_t)M_ * 3 * D_ * 2;        // [8192][3072]
  bf16* ao    = (bf16*)ws;                                       // [8192][1024] attn out
  bf16* xb    = ao;            // x in bf16 time-shares the slot (dead after QKV gemm)

  prep<<<4096 + 768 + 256, 256, 0, stream>>>(x, Wqkv, Wout, xb, WqkvT, WoutT);
  gemm64<false><<<dim3(M_ / 128, 3 * D_ / 128), 256, 0, stream>>>(
      xb, WqkvT, bqkv, qkv, nullptr, nullptr, 3 * D_, D_, D_, 3 * D_);
  attn_db<<<B_ * H_ * (T_ / 128), 256, 0, stream>>>(qkv, ao);
  gemm64<true><<<dim3(M_ / 128, D_ / 128), 256, 0, stream>>>(
      ao, WoutT, bout, nullptr, out, x, D_, D_, D_, D_);
  ln_out<<<M_ / 4, 256, 0, stream>>>(out, gamma, beta);
}